// Round 1
// baseline (1837.956 us; speedup 1.0000x reference)
//
#include <hip/hip_runtime.h>

// Problem constants (fixed by setup_inputs): x (4, 64, 8192, 1) fp32, k=9, dilation=1
#define BB 4
#define DD 64
#define NN 8192
#define KK 9
#define S_SPLITS 4

// ---------------- Kernel 1: L2-normalize + pack to (b*N+n, 64) + per-point sq ----
__global__ __launch_bounds__(256) void knorm_kernel(const float* __restrict__ x,
                                                    float* __restrict__ xnT,
                                                    float* __restrict__ sq) {
    int t = blockIdx.x * 256 + threadIdx.x;      // row id 0..B*N-1
    int b = t >> 13;                             // / 8192
    int n = t & (NN - 1);
    const float* xb = x + (size_t)b * DD * NN + n;
    float v[DD];
    float ss = 0.0f;
#pragma unroll
    for (int d = 0; d < DD; ++d) {
        v[d] = xb[(size_t)d * NN];               // coalesced across lanes
        ss = fmaf(v[d], v[d], ss);
    }
    float norm = sqrtf(ss);
    float inv = 1.0f / fmaxf(norm, 1e-12f);
    float s2 = 0.0f;
#pragma unroll
    for (int d = 0; d < DD; ++d) {
        float xv = v[d] * inv;
        v[d] = xv;
        s2 = fmaf(xv, xv, s2);
    }
    float4* o4 = reinterpret_cast<float4*>(xnT + (size_t)t * DD);
#pragma unroll
    for (int d = 0; d < DD; d += 4) {
        o4[d >> 2] = make_float4(v[d], v[d + 1], v[d + 2], v[d + 3]);
    }
    sq[t] = s2;
}

// ---------------- Kernel 2: fused distance scan + per-split top-9 ---------------
// One thread per row; all lanes of a wave iterate the same (wave-uniform) column j,
// so the column data + sq[j] should lower to scalar (SMEM) loads.
__global__ __launch_bounds__(256) void kdist_kernel(const float* __restrict__ xnT,
                                                    const float* __restrict__ sq,
                                                    unsigned long long* __restrict__ cand) {
    const int rb = blockIdx.x;                   // 0..127 (32 rowblocks per batch)
    const int b = rb >> 5;                       // uniform (from blockIdx only)
    const int nbase = (rb & 31) * 256;
    const int n = nbase + threadIdx.x;
    const int s = blockIdx.y;                    // split id
    const int jcount = NN / S_SPLITS;
    const int j0 = s * jcount;
    const int j1 = j0 + jcount;

    const float* __restrict__ Bb = xnT + ((size_t)b * NN) * DD;  // uniform base
    const float* __restrict__ sqb = sq + (size_t)b * NN;         // uniform base

    // Cache this thread's row in registers.
    float ar[DD];
    {
        const float4* a4 = reinterpret_cast<const float4*>(Bb + (size_t)n * DD);
#pragma unroll
        for (int d = 0; d < DD; d += 4) {
            float4 f = a4[d >> 2];
            ar[d] = f.x; ar[d + 1] = f.y; ar[d + 2] = f.z; ar[d + 3] = f.w;
        }
    }

    // Top-9 as sorted ascending packed u64: (sortable key bits << 32) | j.
    unsigned long long kd[KK];
#pragma unroll
    for (int m = 0; m < KK; ++m) kd[m] = ~0ULL;

#pragma unroll 2
    for (int j = j0; j < j1; ++j) {
        const float4* bc4 = reinterpret_cast<const float4*>(Bb + (size_t)j * DD); // uniform
        float a0 = 0.0f, a1 = 0.0f, a2 = 0.0f, a3 = 0.0f;
#pragma unroll
        for (int d4 = 0; d4 < DD / 4; ++d4) {
            float4 f = bc4[d4];
            a0 = fmaf(ar[4 * d4 + 0], f.x, a0);
            a1 = fmaf(ar[4 * d4 + 1], f.y, a1);
            a2 = fmaf(ar[4 * d4 + 2], f.z, a2);
            a3 = fmaf(ar[4 * d4 + 3], f.w, a3);
        }
        float dot = (a0 + a1) + (a2 + a3);
        float key = fmaf(-2.0f, dot, sqb[j]);    // sq_j - 2*dot  (sq_i is a per-row const)
        unsigned int ub = __float_as_uint(key);
        ub ^= (0x80000000u | (unsigned int)((int)ub >> 31));   // order-preserving map
        unsigned long long cnd = ((unsigned long long)ub << 32) | (unsigned int)j;
        if (cnd < kd[KK - 1]) {
#pragma unroll
            for (int m = 0; m < KK; ++m) {
                bool sw = cnd < kd[m];
                unsigned long long lo = sw ? cnd : kd[m];
                unsigned long long hi = sw ? kd[m] : cnd;
                kd[m] = lo;
                cnd = hi;
            }
        }
    }

    unsigned long long* out = cand + ((size_t)(b * NN + n) * S_SPLITS + s) * KK;
#pragma unroll
    for (int m = 0; m < KK; ++m) out[m] = kd[m];
}

// ---------------- Kernel 3: merge splits, emit edge_index -----------------------
__global__ __launch_bounds__(256) void kmerge_kernel(const unsigned long long* __restrict__ cand,
                                                     int* __restrict__ out) {
    int t = blockIdx.x * 256 + threadIdx.x;      // row id 0..B*N-1
    const unsigned long long* c = cand + (size_t)t * (S_SPLITS * KK);
    unsigned long long kd[KK];
#pragma unroll
    for (int m = 0; m < KK; ++m) kd[m] = ~0ULL;
#pragma unroll
    for (int q = 0; q < S_SPLITS * KK; ++q) {
        unsigned long long cnd = c[q];
        if (cnd < kd[KK - 1]) {
#pragma unroll
            for (int m = 0; m < KK; ++m) {
                bool sw = cnd < kd[m];
                unsigned long long lo = sw ? cnd : kd[m];
                unsigned long long hi = sw ? kd[m] : cnd;
                kd[m] = lo;
                cnd = hi;
            }
        }
    }
    int n = t & (NN - 1);
    int* out0 = out + (size_t)t * KK;                           // nn_idx part
    int* out1 = out + (size_t)BB * NN * KK + (size_t)t * KK;    // center part
#pragma unroll
    for (int m = 0; m < KK; ++m) {
        out0[m] = (int)(kd[m] & 0xFFFFFFFFULL);
        out1[m] = n;
    }
}

extern "C" void kernel_launch(void* const* d_in, const int* in_sizes, int n_in,
                              void* d_out, int out_size, void* d_ws, size_t ws_size,
                              hipStream_t stream) {
    const float* x = (const float*)d_in[0];
    // d_in[1] (k) and d_in[2] (dilation) are fixed: 9, 1.
    int* out = (int*)d_out;

    // Workspace layout
    char* ws = (char*)d_ws;
    float* xnT = (float*)ws;                                     // B*N*D*4   = 8 MB
    float* sq = (float*)(ws + (size_t)BB * NN * DD * 4);         // B*N*4     = 128 KB
    unsigned long long* cand =
        (unsigned long long*)(ws + (size_t)BB * NN * DD * 4 + (size_t)BB * NN * 4);
    // cand: B*N * S_SPLITS * 9 * 8 B = 9.4 MB; total < 18 MB

    knorm_kernel<<<dim3(BB * NN / 256), dim3(256), 0, stream>>>(x, xnT, sq);
    kdist_kernel<<<dim3(BB * NN / 256, S_SPLITS), dim3(256), 0, stream>>>(xnT, sq, cand);
    kmerge_kernel<<<dim3(BB * NN / 256), dim3(256), 0, stream>>>(cand, out);
}

// Round 2
// 1124.042 us; speedup vs baseline: 1.6351x; 1.6351x over previous
//
#include <hip/hip_runtime.h>

// Problem constants (fixed by setup_inputs): x (4, 64, 8192, 1) fp32, k=9, dilation=1
#define BB 4
#define DD 64
#define NN 8192
#define KK 9

// ---------------- Kernel 1: L2-normalize + pack to (b*N+n, 64) + per-point sq ----
__global__ __launch_bounds__(256) void knorm_kernel(const float* __restrict__ x,
                                                    float* __restrict__ xnT,
                                                    float* __restrict__ sq) {
    int t = blockIdx.x * 256 + threadIdx.x;      // row id 0..B*N-1
    int b = t >> 13;                             // / 8192
    int n = t & (NN - 1);
    const float* xb = x + (size_t)b * DD * NN + n;
    float v[DD];
    float ss = 0.0f;
#pragma unroll
    for (int d = 0; d < DD; ++d) {
        v[d] = xb[(size_t)d * NN];               // coalesced across lanes
        ss = fmaf(v[d], v[d], ss);
    }
    float norm = sqrtf(ss);
    float inv = 1.0f / fmaxf(norm, 1e-12f);
    float s2 = 0.0f;
#pragma unroll
    for (int d = 0; d < DD; ++d) {
        float xv = v[d] * inv;
        v[d] = xv;
        s2 = fmaf(xv, xv, s2);
    }
    float4* o4 = reinterpret_cast<float4*>(xnT + (size_t)t * DD);
#pragma unroll
    for (int d = 0; d < DD; d += 4) {
        o4[d >> 2] = make_float4(v[d], v[d + 1], v[d + 2], v[d + 3]);
    }
    sq[t] = s2;
}

// ---------------- Kernel 2: fused distance scan + per-split top-9 ---------------
// One thread per row. All lanes of a wave iterate the same (wave-uniform) column j,
// so the column data + sq[j] lower to scalar (SMEM) loads; the row is pinned in
// VGPRs via opaque asm so the allocator cannot rematerialize it as global loads.
template <int S>
__global__ __launch_bounds__(256, 2) void kdist_kernel(const float* __restrict__ xnT,
                                                       const float* __restrict__ sq,
                                                       unsigned long long* __restrict__ cand) {
    const int rb = blockIdx.x;                   // 0..127 (32 rowblocks per batch)
    const int b = rb >> 5;                       // uniform (from blockIdx only)
    const int nbase = (rb & 31) * 256;
    const int n = nbase + threadIdx.x;
    const int s = blockIdx.y;                    // split id
    const int jcount = NN / S;
    const int j0 = s * jcount;
    const int j1 = j0 + jcount;

    const float* __restrict__ Bb = xnT + ((size_t)b * NN) * DD;  // uniform base
    const float* __restrict__ sqb = sq + (size_t)b * NN;         // uniform base

    // Cache this thread's row in registers — and PIN it there (see post-mortem:
    // without the asm the allocator rematerializes these as per-iteration
    // global loads to hit a high-occupancy VGPR budget; VGPR_Count was 52).
    float ar[DD];
    {
        const float4* a4 = reinterpret_cast<const float4*>(Bb + (size_t)n * DD);
#pragma unroll
        for (int d = 0; d < DD; d += 4) {
            float4 f = a4[d >> 2];
            ar[d] = f.x; ar[d + 1] = f.y; ar[d + 2] = f.z; ar[d + 3] = f.w;
        }
    }
#pragma unroll
    for (int d = 0; d < DD; ++d) {
        asm volatile("" : "+v"(ar[d]));
    }

    // Top-9 as sorted ascending packed u64: (sortable key bits << 32) | j.
    // Strict-less comparisons reproduce top_k's lower-index-first tie rule.
    unsigned long long kd[KK];
#pragma unroll
    for (int m = 0; m < KK; ++m) kd[m] = ~0ULL;

#pragma unroll 2
    for (int j = j0; j < j1; ++j) {
        const float4* bc4 = reinterpret_cast<const float4*>(Bb + (size_t)j * DD); // uniform
        float a0 = 0.0f, a1 = 0.0f, a2 = 0.0f, a3 = 0.0f;
#pragma unroll
        for (int d4 = 0; d4 < DD / 4; ++d4) {
            float4 f = bc4[d4];
            a0 = fmaf(ar[4 * d4 + 0], f.x, a0);
            a1 = fmaf(ar[4 * d4 + 1], f.y, a1);
            a2 = fmaf(ar[4 * d4 + 2], f.z, a2);
            a3 = fmaf(ar[4 * d4 + 3], f.w, a3);
        }
        float dot = (a0 + a1) + (a2 + a3);
        float key = fmaf(-2.0f, dot, sqb[j]);    // sq_j - 2*dot  (sq_i is a per-row const)
        unsigned int ub = __float_as_uint(key);
        ub ^= (0x80000000u | (unsigned int)((int)ub >> 31));   // order-preserving map
        unsigned long long cnd = ((unsigned long long)ub << 32) | (unsigned int)j;
        if (cnd < kd[KK - 1]) {
#pragma unroll
            for (int m = 0; m < KK; ++m) {
                bool sw = cnd < kd[m];
                unsigned long long lo = sw ? cnd : kd[m];
                unsigned long long hi = sw ? kd[m] : cnd;
                kd[m] = lo;
                cnd = hi;
            }
        }
    }

    unsigned long long* out = cand + ((size_t)(b * NN + n) * S + s) * KK;
#pragma unroll
    for (int m = 0; m < KK; ++m) out[m] = kd[m];
}

// ---------------- Kernel 3: merge splits, emit edge_index -----------------------
template <int S>
__global__ __launch_bounds__(256) void kmerge_kernel(const unsigned long long* __restrict__ cand,
                                                     int* __restrict__ out) {
    int t = blockIdx.x * 256 + threadIdx.x;      // row id 0..B*N-1
    const unsigned long long* c = cand + (size_t)t * (S * KK);
    unsigned long long kd[KK];
#pragma unroll
    for (int m = 0; m < KK; ++m) kd[m] = ~0ULL;
#pragma unroll
    for (int q = 0; q < S * KK; ++q) {
        unsigned long long cnd = c[q];
        if (cnd < kd[KK - 1]) {
#pragma unroll
            for (int m = 0; m < KK; ++m) {
                bool sw = cnd < kd[m];
                unsigned long long lo = sw ? cnd : kd[m];
                unsigned long long hi = sw ? kd[m] : cnd;
                kd[m] = lo;
                cnd = hi;
            }
        }
    }
    int n = t & (NN - 1);
    int* out0 = out + (size_t)t * KK;                           // nn_idx part
    int* out1 = out + (size_t)BB * NN * KK + (size_t)t * KK;    // center part
#pragma unroll
    for (int m = 0; m < KK; ++m) {
        out0[m] = (int)(kd[m] & 0xFFFFFFFFULL);
        out1[m] = n;
    }
}

extern "C" void kernel_launch(void* const* d_in, const int* in_sizes, int n_in,
                              void* d_out, int out_size, void* d_ws, size_t ws_size,
                              hipStream_t stream) {
    const float* x = (const float*)d_in[0];
    // d_in[1] (k) and d_in[2] (dilation) are fixed: 9, 1.
    int* out = (int*)d_out;

    // Workspace layout
    char* ws = (char*)d_ws;
    float* xnT = (float*)ws;                                     // B*N*D*4   = 8 MB
    float* sq = (float*)(ws + (size_t)BB * NN * DD * 4);         // B*N*4     = 128 KB
    unsigned long long* cand =
        (unsigned long long*)(ws + (size_t)BB * NN * DD * 4 + (size_t)BB * NN * 4);

    const size_t base = (size_t)BB * NN * DD * 4 + (size_t)BB * NN * 4;
    const size_t need8 = base + (size_t)BB * NN * 8 * KK * 8;    // ~27 MB with S=8

    knorm_kernel<<<dim3(BB * NN / 256), dim3(256), 0, stream>>>(x, xnT, sq);
    if (ws_size >= need8) {
        kdist_kernel<8><<<dim3(BB * NN / 256, 8), dim3(256), 0, stream>>>(xnT, sq, cand);
        kmerge_kernel<8><<<dim3(BB * NN / 256), dim3(256), 0, stream>>>(cand, out);
    } else {
        kdist_kernel<4><<<dim3(BB * NN / 256, 4), dim3(256), 0, stream>>>(xnT, sq, cand);
        kmerge_kernel<4><<<dim3(BB * NN / 256), dim3(256), 0, stream>>>(cand, out);
    }
}